// Round 1
// baseline (300.731 us; speedup 1.0000x reference)
//
#include <hip/hip_runtime.h>

// OptPosEncVol: trilinear interpolation of a dense 64^3 x 64ch fp32 grid.
// coords: [8, 65536, 3] fp32 in [0,1) -> c = (x+1)*31.5 in [31.5, 63)
// shape_code: [64, 262144] fp32 (channel-major -> we transpose to ws)
// out: [8, 65536, 64] fp32
//
// Strategy:
//  1) transpose_k: shape_code [C][T] -> ws [T][C] so each corner's 64-channel
//     vector is a contiguous 256B block (wave-coalesced gather, lane=channel).
//  2) interp_k: one wave per point. All 64 lanes redundantly compute the 8
//     corner indices + weights (broadcast loads), then 8 independent coalesced
//     256B gathers, FMA-accumulate, one coalesced 256B store.

#define CODE_NUM 64
#define CODE_CHANNEL 64
#define TABLE (CODE_NUM * CODE_NUM * CODE_NUM)  // 262144

__global__ __launch_bounds__(256) void transpose_k(const float* __restrict__ src,
                                                   float* __restrict__ dst) {
    // src: [64][TABLE], dst: [TABLE][64]. One block transposes a 64x64 tile.
    __shared__ float tile[64][65];  // +1 pad: conflict-free
    const int t0 = blockIdx.x * 64;
    const int tx = threadIdx.x & 63;
    const int ty = threadIdx.x >> 6;  // 0..3
#pragma unroll
    for (int i = 0; i < 16; ++i) {
        const int c = (i << 2) | ty;                       // channel 0..63
        tile[c][tx] = src[(size_t)c * TABLE + t0 + tx];    // coalesced 256B rows
    }
    __syncthreads();
#pragma unroll
    for (int i = 0; i < 16; ++i) {
        const int t = (i << 2) | ty;
        dst[(size_t)(t0 + t) * 64 + tx] = tile[tx][t];     // coalesced 256B rows
    }
}

template <bool TRANSPOSED>
__global__ __launch_bounds__(256) void interp_k(const float* __restrict__ coords,
                                                const float* __restrict__ table,
                                                const int* __restrict__ idxp,
                                                float* __restrict__ out,
                                                int npoints) {
    const int p = (int)((blockIdx.x * 256u + threadIdx.x) >> 6);
    const int lane = threadIdx.x & 63;
    if (p >= npoints) return;

    const int offset = idxp[0] * TABLE;

    // Broadcast loads (all 64 lanes same address -> single transaction each).
    const float sx = (coords[p * 3 + 0] + 1.0f) * ((CODE_NUM - 1) * 0.5f);
    const float sy = (coords[p * 3 + 1] + 1.0f) * ((CODE_NUM - 1) * 0.5f);
    const float sz = (coords[p * 3 + 2] + 1.0f) * ((CODE_NUM - 1) * 0.5f);

    const float fx = floorf(sx), fy = floorf(sy), fz = floorf(sz);
    const float rx = sx - fx, ry = sy - fy, rz = sz - fz;
    const int ix = (int)fx, iy = (int)fy, iz = (int)fz;
    const int base = offset + ix + iy * CODE_NUM + iz * (CODE_NUM * CODE_NUM);

    const float wx[2] = {1.0f - rx, rx};
    const float wy[2] = {1.0f - ry, ry};
    const float wz[2] = {1.0f - rz, rz};

    // 8 independent gathers -> ILP; compiler software-pipelines the loads.
    float acc = 0.0f;
#pragma unroll
    for (int k = 0; k < 8; ++k) {
        const int a = k & 1, b = (k >> 1) & 1, c = (k >> 2) & 1;
        const int idx = base + a + b * CODE_NUM + c * (CODE_NUM * CODE_NUM);
        const float w = wx[a] * wy[b] * wz[c];
        float v;
        if (TRANSPOSED) {
            v = table[(size_t)idx * CODE_CHANNEL + lane];   // coalesced 256B
        } else {
            v = table[(size_t)lane * TABLE + idx];          // fallback: strided
        }
        acc = fmaf(w, v, acc);
    }
    out[(size_t)p * CODE_CHANNEL + lane] = acc;  // coalesced 256B per wave
}

extern "C" void kernel_launch(void* const* d_in, const int* in_sizes, int n_in,
                              void* d_out, int out_size, void* d_ws, size_t ws_size,
                              hipStream_t stream) {
    const float* coords = (const float*)d_in[0];
    const float* code   = (const float*)d_in[1];
    const int*   idxp   = (const int*)d_in[2];
    float* out = (float*)d_out;

    const int npoints = in_sizes[0] / 3;  // 8 * 65536 = 524288
    const size_t tbytes = (size_t)TABLE * CODE_CHANNEL * sizeof(float);  // 64 MB

    if (ws_size >= tbytes) {
        float* tt = (float*)d_ws;
        transpose_k<<<TABLE / 64, 256, 0, stream>>>(code, tt);
        interp_k<true><<<(npoints + 3) / 4, 256, 0, stream>>>(coords, tt, idxp, out, npoints);
    } else {
        // Workspace too small: correct-but-slower path on the original layout.
        interp_k<false><<<(npoints + 3) / 4, 256, 0, stream>>>(coords, code, idxp, out, npoints);
    }
}

// Round 2
// 280.930 us; speedup vs baseline: 1.0705x; 1.0705x over previous
//
#include <hip/hip_runtime.h>

// OptPosEncVol: trilinear interpolation of a dense 64^3 x 64ch fp32 grid.
// coords: [8, 65536, 3] fp32 in [0,1) -> c = (x+1)*31.5 in [31.5, 63)
// shape_code: [64, 262144] fp32 (channel-major -> transposed into ws)
// out: [8, 65536, 64] fp32
//
// R2 design:
//  transpose_k: [C][T] -> ws [T][C], float4 global accesses on both sides,
//    LDS staging with b32 ops (<=2-way bank aliasing, which is free on gfx950).
//  interp_k: 4 points per wave. lane l -> point l>>4, channels 4*(l&15)..+3.
//    Each corner gather: 16 lanes x 16B = full 256B corner row; one wave
//    instruction covers 4 points (1KB). 8 independent dwordx4 gathers in
//    flight, no cross-lane reduce, one coalesced 1KB float4 store per wave.

#define CODE_NUM 64
#define CODE_CHANNEL 64
#define TABLE (CODE_NUM * CODE_NUM * CODE_NUM)  // 262144

__global__ __launch_bounds__(256) void transpose_k(const float* __restrict__ src,
                                                   float* __restrict__ dst) {
    // One block transposes a 64t x 64c tile. tile[t][c] at t*65+c (S=65:
    // scalar LDS ops land <=2-way per wave instr on both sides -> free).
    __shared__ float tile[64 * 65];
    const int t0 = blockIdx.x * 64;
    const int j = threadIdx.x;

    // Load: q = i*256+j in [0,1024): row c=q>>4, tcol4=q&15.
    // Global read float4 (4 x 256B contiguous segments per wave instr).
#pragma unroll
    for (int i = 0; i < 4; ++i) {
        const int q = (i << 8) | j;
        const int c = q >> 4;
        const int tc4 = q & 15;
        const float4 v = *(const float4*)(src + (size_t)c * TABLE + t0 + (tc4 << 2));
        tile[((tc4 << 2) + 0) * 65 + c] = v.x;
        tile[((tc4 << 2) + 1) * 65 + c] = v.y;
        tile[((tc4 << 2) + 2) * 65 + c] = v.z;
        tile[((tc4 << 2) + 3) * 65 + c] = v.w;
    }
    __syncthreads();

    // Store: q: t=q>>4, c4=q&15. Wave writes 1KB contiguous float4.
#pragma unroll
    for (int i = 0; i < 4; ++i) {
        const int q = (i << 8) | j;
        const int t = q >> 4;
        const int c4 = q & 15;
        float4 v;
        v.x = tile[t * 65 + (c4 << 2) + 0];
        v.y = tile[t * 65 + (c4 << 2) + 1];
        v.z = tile[t * 65 + (c4 << 2) + 2];
        v.w = tile[t * 65 + (c4 << 2) + 3];
        *(float4*)(dst + (size_t)(t0 + t) * 64 + (c4 << 2)) = v;
    }
}

// 4 points per wave, float4 channels per lane.
__global__ __launch_bounds__(256) void interp4_k(const float* __restrict__ coords,
                                                 const float* __restrict__ table,
                                                 const int* __restrict__ idxp,
                                                 float* __restrict__ out,
                                                 int npoints) {
    const unsigned tid = blockIdx.x * 256u + threadIdx.x;
    const int lane = threadIdx.x & 63;
    const int sub = lane >> 4;       // point within wave (0..3)
    const int cg = lane & 15;        // channel group: channels 4*cg..4*cg+3
    const int p = (int)((tid >> 6) * 4u + (unsigned)sub);
    if (p >= npoints) return;

    const int offset = idxp[0] * TABLE;

    const float sx = (coords[p * 3 + 0] + 1.0f) * ((CODE_NUM - 1) * 0.5f);
    const float sy = (coords[p * 3 + 1] + 1.0f) * ((CODE_NUM - 1) * 0.5f);
    const float sz = (coords[p * 3 + 2] + 1.0f) * ((CODE_NUM - 1) * 0.5f);

    const float fx = floorf(sx), fy = floorf(sy), fz = floorf(sz);
    const float rx = sx - fx, ry = sy - fy, rz = sz - fz;
    const int ix = (int)fx, iy = (int)fy, iz = (int)fz;
    const int base = offset + ix + iy * CODE_NUM + iz * (CODE_NUM * CODE_NUM);

    const float wx[2] = {1.0f - rx, rx};
    const float wy[2] = {1.0f - ry, ry};
    const float wz[2] = {1.0f - rz, rz};

    // Byte addressing: idx*256 + cg*16 < 67MB fits in 32-bit offset.
    const char* tp = (const char*)table;
    const int cgoff = cg << 4;

    float4 acc = make_float4(0.f, 0.f, 0.f, 0.f);
#pragma unroll
    for (int k = 0; k < 8; ++k) {
        const int a = k & 1, b = (k >> 1) & 1, c = (k >> 2) & 1;
        const int idx = base + a + b * CODE_NUM + c * (CODE_NUM * CODE_NUM);
        const float w = wx[a] * wy[b] * wz[c];
        const float4 v = *(const float4*)(tp + ((size_t)(unsigned)(idx << 8) + cgoff));
        acc.x = fmaf(w, v.x, acc.x);
        acc.y = fmaf(w, v.y, acc.y);
        acc.z = fmaf(w, v.z, acc.z);
        acc.w = fmaf(w, v.w, acc.w);
    }
    *(float4*)(out + (size_t)p * CODE_CHANNEL + (cg << 2)) = acc;  // 1KB/wave
}

// Fallback for tiny workspace: original layout, lane=channel.
__global__ __launch_bounds__(256) void interp_fallback_k(const float* __restrict__ coords,
                                                         const float* __restrict__ table,
                                                         const int* __restrict__ idxp,
                                                         float* __restrict__ out,
                                                         int npoints) {
    const int p = (int)((blockIdx.x * 256u + threadIdx.x) >> 6);
    const int lane = threadIdx.x & 63;
    if (p >= npoints) return;
    const int offset = idxp[0] * TABLE;
    const float sx = (coords[p * 3 + 0] + 1.0f) * ((CODE_NUM - 1) * 0.5f);
    const float sy = (coords[p * 3 + 1] + 1.0f) * ((CODE_NUM - 1) * 0.5f);
    const float sz = (coords[p * 3 + 2] + 1.0f) * ((CODE_NUM - 1) * 0.5f);
    const float fx = floorf(sx), fy = floorf(sy), fz = floorf(sz);
    const float rx = sx - fx, ry = sy - fy, rz = sz - fz;
    const int base = offset + (int)fx + (int)fy * CODE_NUM + (int)fz * (CODE_NUM * CODE_NUM);
    const float wx[2] = {1.0f - rx, rx};
    const float wy[2] = {1.0f - ry, ry};
    const float wz[2] = {1.0f - rz, rz};
    float acc = 0.0f;
#pragma unroll
    for (int k = 0; k < 8; ++k) {
        const int a = k & 1, b = (k >> 1) & 1, c = (k >> 2) & 1;
        const int idx = base + a + b * CODE_NUM + c * (CODE_NUM * CODE_NUM);
        acc = fmaf(wx[a] * wy[b] * wz[c], table[(size_t)lane * TABLE + idx], acc);
    }
    out[(size_t)p * CODE_CHANNEL + lane] = acc;
}

extern "C" void kernel_launch(void* const* d_in, const int* in_sizes, int n_in,
                              void* d_out, int out_size, void* d_ws, size_t ws_size,
                              hipStream_t stream) {
    const float* coords = (const float*)d_in[0];
    const float* code   = (const float*)d_in[1];
    const int*   idxp   = (const int*)d_in[2];
    float* out = (float*)d_out;

    const int npoints = in_sizes[0] / 3;  // 524288
    const size_t tbytes = (size_t)TABLE * CODE_CHANNEL * sizeof(float);  // 64 MB

    if (ws_size >= tbytes) {
        float* tt = (float*)d_ws;
        transpose_k<<<TABLE / 64, 256, 0, stream>>>(code, tt);
        // 16 points per 256-thread block (4 waves x 4 points).
        interp4_k<<<(npoints + 15) / 16, 256, 0, stream>>>(coords, tt, idxp, out, npoints);
    } else {
        interp_fallback_k<<<(npoints + 3) / 4, 256, 0, stream>>>(coords, code, idxp, out, npoints);
    }
}